// Round 7
// baseline (36.731 us; speedup 1.0000x reference)
//
#include <hip/hip_runtime.h>
#include <math.h>

#define VOCAB 100000
#define EMB 128
#define BATCH 16384
#define NPOS 4
#define NNEG 20
#define EPSV 1e-3f

#define NTHREADS 256
#define WPB (NTHREADS / 64)       // 4 waves/block, one batch elem per wave
#define NBLOCKS (BATCH / WPB)     // 4096

__device__ __forceinline__ float dot4(float4 a, float4 b) {
    return a.x * b.x + a.y * b.y + a.z * b.z + a.w * b.w;
}

// One wave per batch element, (sample x chunk) layout: sg = lane>>3 owns
// sample g*8+sg, c = lane&7 owns chunks {c, c+8, c+16, c+24}.
// ALL 16 row-load instructions (12 W + 4 emb) are issued before any use:
// 64 VGPR of load destinations in flight per wave (launch_bounds(...,2)
// permits ~128 VGPR). This is the MLP experiment rounds 3/4 accidentally
// suppressed with tight launch_bounds VGPR caps.
__global__ __launch_bounds__(NTHREADS, 2) void w2v_main(
    const int* __restrict__ x,
    const int* __restrict__ pos,
    const int* __restrict__ neg,
    const float* __restrict__ emb,
    const float* __restrict__ outw,
    float* __restrict__ partials)
{
    const int tid  = threadIdx.x;
    const int lane = tid & 63;
    const int wid  = tid >> 6;
    const int sg   = lane >> 3;   // 0..7: sample-in-group
    const int c    = lane & 7;    // 0..7: chunk lane

    const int b  = blockIdx.x * WPB + wid;  // batch element (wave-uniform)
    const int xb = x[b];

    // Sample indices for groups 0..2 (8 lanes share each address; TA dedups).
    const int idx0 = (sg < NPOS) ? pos[b * NPOS + sg] : neg[b * NNEG + (sg - NPOS)];
    const int idx1 = neg[b * NNEG + (8  + sg - NPOS)];
    const int idx2 = neg[b * NNEG + (16 + sg - NPOS)];

    const float4* er  = (const float4*)(emb  + ((long)xb   << 7));
    const float4* w0r = (const float4*)(outw + ((long)idx0 << 7));
    const float4* w1r = (const float4*)(outw + ((long)idx1 << 7));
    const float4* w2r = (const float4*)(outw + ((long)idx2 << 7));

    // ---- issue ALL loads (16 independent global_load_dwordx4) ----
    const float4 a0 = w0r[c];      const float4 a1 = w0r[c + 8];
    const float4 a2 = w0r[c + 16]; const float4 a3 = w0r[c + 24];
    const float4 b0 = w1r[c];      const float4 b1 = w1r[c + 8];
    const float4 b2 = w1r[c + 16]; const float4 b3 = w1r[c + 24];
    const float4 c0 = w2r[c];      const float4 c1 = w2r[c + 8];
    const float4 c2 = w2r[c + 16]; const float4 c3 = w2r[c + 24];
    const float4 e0 = er[c];       const float4 e1 = er[c + 8];
    const float4 e2 = er[c + 16];  const float4 e3 = er[c + 24];

    // ---- dots (in-register over chunks) ----
    float d0 = dot4(e0, a0) + dot4(e1, a1) + dot4(e2, a2) + dot4(e3, a3);
    float d1 = dot4(e0, b0) + dot4(e1, b1) + dot4(e2, b2) + dot4(e3, b3);
    float d2 = dot4(e0, c0) + dot4(e1, c1) + dot4(e2, c2) + dot4(e3, c3);

    // ---- 8-lane butterfly per group (all 8 lanes end with the sum) ----
    d0 += __shfl_xor(d0, 1); d0 += __shfl_xor(d0, 2); d0 += __shfl_xor(d0, 4);
    d1 += __shfl_xor(d1, 1); d1 += __shfl_xor(d1, 2); d1 += __shfl_xor(d1, 4);
    d2 += __shfl_xor(d2, 1); d2 += __shfl_xor(d2, 2); d2 += __shfl_xor(d2, 4);

    // ---- transcendental tail: lane c==g finalizes sample g*8+sg ----
    float pacc = 0.0f, nacc = 0.0f;
    if (c < 3) {
        const float zz = (c == 0) ? d0 : ((c == 1) ? d1 : d2);
        const int   s  = c * 8 + sg;
        const float sig = 1.0f / (1.0f + __expf(-zz));
        if (s < NPOS) pacc = __logf(sig);
        else          nacc = __logf(1.0f - sig + EPSV);
    }

    // ---- wave-wide butterfly (sums all active lanes) ----
#pragma unroll
    for (int m = 1; m < 64; m <<= 1) {
        pacc += __shfl_xor(pacc, m);
        nacc += __shfl_xor(nacc, m);
    }

    __shared__ float sp[WPB];
    __shared__ float sn[WPB];
    if (lane == 0) { sp[wid] = pacc; sn[wid] = nacc; }
    __syncthreads();
    if (tid == 0) {
        float tp = 0.0f, tn = 0.0f;
#pragma unroll
        for (int w = 0; w < WPB; ++w) { tp += sp[w]; tn += sn[w]; }
        ((float2*)partials)[blockIdx.x] = make_float2(tp, tn);
    }
}

// Finalize: single block reduces 4096 float2 partials, writes the scalar loss.
__global__ __launch_bounds__(1024) void w2v_final(
    const float* __restrict__ partials, float* __restrict__ out)
{
    const int tid  = threadIdx.x;
    const int lane = tid & 63;
    const int wid  = tid >> 6;

    float tp = 0.0f, tn = 0.0f;
    for (int k = tid; k < NBLOCKS; k += 1024) {
        const float2 v = ((const float2*)partials)[k];
        tp += v.x;
        tn += v.y;
    }
#pragma unroll
    for (int m = 1; m < 64; m <<= 1) {
        tp += __shfl_xor(tp, m);
        tn += __shfl_xor(tn, m);
    }
    __shared__ float sp[16];
    __shared__ float sn[16];
    if (lane == 0) { sp[wid] = tp; sn[wid] = tn; }
    __syncthreads();
    if (tid == 0) {
        float fp = 0.0f, fn = 0.0f;
#pragma unroll
        for (int w = 0; w < 16; ++w) { fp += sp[w]; fn += sn[w]; }
        out[0] = -fp / (float)(BATCH * NPOS) - fn / (float)(BATCH * NNEG);
    }
}

extern "C" void kernel_launch(void* const* d_in, const int* in_sizes, int n_in,
                              void* d_out, int out_size, void* d_ws, size_t ws_size,
                              hipStream_t stream) {
    const int*   x    = (const int*)d_in[0];
    const int*   pos  = (const int*)d_in[1];
    const int*   neg  = (const int*)d_in[2];
    const float* emb  = (const float*)d_in[3];
    const float* outw = (const float*)d_in[4];
    float* out = (float*)d_out;
    float* partials = (float*)d_ws;   // 4096 float2, fully rewritten each launch

    w2v_main<<<NBLOCKS, NTHREADS, 0, stream>>>(x, pos, neg, emb, outw, partials);
    w2v_final<<<1, 1024, 0, stream>>>(partials, out);
}